// Round 11
// baseline (322.571 us; speedup 1.0000x reference)
//
#include <hip/hip_runtime.h>
#include <hip/hip_bf16.h>
#include <cstdint>

// Problem: single attention head, B=4 T=2048 C=1024 H=128, causal, scale = C^-0.5.
// Inputs fp32: x[B,T,C], Wq/Wk/Wv[C,H], mask[T,T] int32 (tril, ignored).
// Output fp32 [B,T,H].
//
// R11: ONE ordinary launch + software grid barrier (R10's cooperative launch
// was silently rejected -> zero output). Co-residency guaranteed: LDS 64KB,
// VGPR<=256 via __launch_bounds__(256,2) -> 2 blocks/CU x 256 CU = 512 = grid.
//   P0: W->Wt[3][H][C] transpose (tiny; x convert ELIMINATED)
//   P1: proj: fp32 A staged straight from x via global_load_lds(16B) dbuf,
//       B from Wt bf16; 64Mx128N/block tile; q pre-scaled by C^-0.5
//   P2: attn (R8 v3 body): 16-row Q tiles, split-KV-4, ones-column l,
//       K/V prefetch, reverse-pair load balance

typedef __bf16 bf16_t;
typedef __bf16 bf16x4 __attribute__((ext_vector_type(4)));
typedef __bf16 bf16x8 __attribute__((ext_vector_type(8)));
typedef float f32x4 __attribute__((ext_vector_type(4)));

#define MFMA16(a, b, c) __builtin_amdgcn_mfma_f32_16x16x32_bf16(a, b, c, 0, 0, 0)

constexpr int T = 2048;
constexpr int C = 1024;
constexpr int H = 128;
constexpr int BK = 64;

__device__ inline void gld16(const void* g, void* l) {
    __builtin_amdgcn_global_load_lds(
        (const __attribute__((address_space(1))) unsigned int*)g,
        (__attribute__((address_space(3))) unsigned int*)l, 16, 0, 0);
}

// software grid barrier: producer-release fence + agent atomic; consumer spin
// + acquire fence. All 512 blocks co-resident (see header) -> no deadlock.
__device__ inline void gbar(int* cnt, int target) {
    __syncthreads();
    if (threadIdx.x == 0) {
        __threadfence();                                   // release
        __hip_atomic_fetch_add(cnt, 1, __ATOMIC_ACQ_REL, __HIP_MEMORY_SCOPE_AGENT);
        while (__hip_atomic_load(cnt, __ATOMIC_ACQUIRE, __HIP_MEMORY_SCOPE_AGENT) < target)
            __builtin_amdgcn_s_sleep(8);
        __threadfence();                                   // acquire
    }
    __syncthreads();
}

union SMem {
    struct { bf16_t tile[32][34]; } tr;                         // 2.2 KB
    struct { float Ab[2][64 * BK]; bf16_t Bb[2][128 * BK]; } pj;  // 32+32 = 64 KB
    struct {
        float accw[4][16][128];                                 // 32 KB
        bf16_t pbuf[4][16][40];                                 // 5 KB
        float mred[4][16], lred[4][16];                         // 0.5 KB
    } at;
};

__global__ __launch_bounds__(256, 2) void fused(const float* __restrict__ x,
                                                const float* __restrict__ Wq,
                                                const float* __restrict__ Wk,
                                                const float* __restrict__ Wv,
                                                bf16_t* __restrict__ Wt,
                                                bf16_t* __restrict__ qb_,
                                                bf16_t* __restrict__ kb_,
                                                bf16_t* __restrict__ vt_,
                                                float* __restrict__ out,
                                                int* __restrict__ flag) {
    __shared__ __align__(16) SMem sm;
    const int tid = threadIdx.x;
    const int blk = blockIdx.x;

    // ================= P0: transpose W (blocks < 384) =================
    if (blk < 384) {
        const int z = blk >> 7, rem = blk & 127;       // 32 c-tiles x 4 h-tiles
        const int c0 = (rem & 31) * 32, h0 = (rem >> 5) * 32;
        const float* W = z == 0 ? Wq : (z == 1 ? Wk : Wv);
        const int tx = tid & 31, ty = tid >> 5;
#pragma unroll
        for (int i = 0; i < 4; i++)
            sm.tr.tile[ty + 8 * i][tx] = (bf16_t)W[(size_t)(c0 + ty + 8 * i) * H + h0 + tx];
        __syncthreads();
        bf16_t* Wtz = Wt + (size_t)z * H * C;
#pragma unroll
        for (int i = 0; i < 4; i++)
            Wtz[(size_t)(h0 + ty + 8 * i) * C + c0 + tx] = sm.tr.tile[tx][ty + 8 * i];
    }
    gbar(flag, 512);

    // ================= P1: proj (blocks < 384) =================
    if (blk < 384) {
        const int w = tid >> 6, lane = tid & 63;
        const int m16 = lane & 15, g = lane >> 4;
        const int wm = w & 1, wn = w >> 1;
        const int z = blk >> 7;                        // 0..2
        const int m0 = (blk & 127) * 64;
        const bf16_t* Bsrc = Wt + (size_t)z * H * C;

        // A: fp32, 64 rows x 16 groups(4 floats); v = c4 ^ (r&15) swizzle.
        // B: bf16, 128 rows x 8 groups(8 bf16); v = c8 ^ (r&7) swizzle.
        auto stage = [&](int s, int k0) {
#pragma unroll
            for (int i = 0; i < 4; i++) {              // A: e in [0,1024)
                const int e = i * 256 + tid;
                const int r = e >> 4, v = e & 15, c4 = v ^ (r & 15);
                gld16(x + (size_t)(m0 + r) * C + k0 + c4 * 4,
                      &sm.pj.Ab[s][(i * 4 + w) * 256]);
            }
#pragma unroll
            for (int i = 0; i < 4; i++) {              // B: e in [0,1024)
                const int e = i * 256 + tid;
                const int r = e >> 3, v = e & 7, c8 = v ^ (r & 7);
                gld16(Bsrc + (size_t)r * C + k0 + c8 * 8,
                      &sm.pj.Bb[s][(i * 4 + w) * 512]);
            }
        };

        f32x4 zero = {0.f, 0.f, 0.f, 0.f};
        f32x4 acc[2][4];
#pragma unroll
        for (int mf = 0; mf < 2; mf++)
#pragma unroll
            for (int nf = 0; nf < 4; nf++) acc[mf][nf] = zero;

        stage(0, 0);
        for (int c = 0; c < C / BK; c++) {
            __syncthreads();
            if (c + 1 < C / BK) stage((c + 1) & 1, (c + 1) * BK);
            const int s = c & 1;

            bf16x8 af[2][2], bfr[4][2];
#pragma unroll
            for (int mf = 0; mf < 2; mf++)
#pragma unroll
                for (int kf = 0; kf < 2; kf++) {
                    const int r = wm * 32 + mf * 16 + m16;
                    const int c4 = kf * 8 + g * 2;
                    const int va = c4 ^ (r & 15), vb = (c4 + 1) ^ (r & 15);
                    float4 fa = *(const float4*)(&sm.pj.Ab[s][r * BK + va * 4]);
                    float4 fb = *(const float4*)(&sm.pj.Ab[s][r * BK + vb * 4]);
                    bf16x8 t;
                    t[0] = (bf16_t)fa.x; t[1] = (bf16_t)fa.y;
                    t[2] = (bf16_t)fa.z; t[3] = (bf16_t)fa.w;
                    t[4] = (bf16_t)fb.x; t[5] = (bf16_t)fb.y;
                    t[6] = (bf16_t)fb.z; t[7] = (bf16_t)fb.w;
                    af[mf][kf] = t;
                }
#pragma unroll
            for (int nf = 0; nf < 4; nf++)
#pragma unroll
                for (int kf = 0; kf < 2; kf++) {
                    const int r = wn * 64 + nf * 16 + m16;
                    const int v = (kf * 4 + g) ^ (r & 7);
                    bfr[nf][kf] = *(const bf16x8*)(&sm.pj.Bb[s][r * BK + v * 8]);
                }
#pragma unroll
            for (int kf = 0; kf < 2; kf++)
#pragma unroll
                for (int mf = 0; mf < 2; mf++)
#pragma unroll
                    for (int nf = 0; nf < 4; nf++)
                        acc[mf][nf] = MFMA16(af[mf][kf], bfr[nf][kf], acc[mf][nf]);
        }

        const float sc = (z == 0) ? 0.03125f : 1.0f;   // fold C^-0.5 into q
        if (z < 2) {
            bf16_t* o = (z == 0) ? qb_ : kb_;
#pragma unroll
            for (int mf = 0; mf < 2; mf++)
#pragma unroll
                for (int nf = 0; nf < 4; nf++)
#pragma unroll
                    for (int ri = 0; ri < 4; ri++) {
                        const int r = m0 + wm * 32 + mf * 16 + g * 4 + ri;
                        const int n = wn * 64 + nf * 16 + m16;
                        o[(size_t)r * H + n] = (bf16_t)(acc[mf][nf][ri] * sc);
                    }
        } else {
#pragma unroll
            for (int mf = 0; mf < 2; mf++) {
                const int t0 = m0 + wm * 32 + mf * 16 + g * 4;
                const int bidx = t0 >> 11, tt = t0 & (T - 1);
#pragma unroll
                for (int nf = 0; nf < 4; nf++) {
                    const int h = wn * 64 + nf * 16 + m16;
                    bf16x4 vv;
#pragma unroll
                    for (int ri = 0; ri < 4; ri++) vv[ri] = (bf16_t)acc[mf][nf][ri];
                    *(bf16x4*)(vt_ + ((size_t)bidx * H + h) * T + tt) = vv;
                }
            }
        }
    }
    gbar(flag, 1024);

    // ================= P2: attn (R8 v3 body) =================
    {
        const int w = tid >> 6;
        const int lane = tid & 63;
        const int m16 = lane & 15, g = lane >> 4;
        const int b = blk & 3;
        const int kk = blk >> 2;                       // 0..127
        const int qt = (kk < 64) ? kk : 191 - kk;      // reverse-pair balance
        const int q0 = qt * 16;

        const bf16_t* qb = qb_ + (size_t)b * T * H;
        const bf16_t* kb = kb_ + (size_t)b * T * H;
        const bf16_t* vb = vt_ + (size_t)b * H * T;

        bf16x8 aq[4];
#pragma unroll
        for (int c = 0; c < 4; c++)
            aq[c] = *(const bf16x8*)(qb + (size_t)(q0 + m16) * H + c * 32 + g * 8);

        bf16x8 ones;
#pragma unroll
        for (int i = 0; i < 8; i++) ones[i] = (bf16_t)1.0f;

        f32x4 zero = {0.f, 0.f, 0.f, 0.f};
        f32x4 acc[9];
#pragma unroll
        for (int ht = 0; ht < 9; ht++) acc[ht] = zero;
        float mst[4];
#pragma unroll
        for (int ri = 0; ri < 4; ri++) mst[ri] = -1e30f;

        const int kv_end = q0 + 16;
        bf16x8 kc[8], kn[8], vc[8];
        int kv0 = w * 32;
        if (kv0 < kv_end) {
#pragma unroll
            for (int t = 0; t < 2; t++)
#pragma unroll
                for (int c = 0; c < 4; c++)
                    kc[t * 4 + c] = *(const bf16x8*)(kb + (size_t)(kv0 + t * 16 + m16) * H + c * 32 + g * 8);
        }

        for (; kv0 < kv_end; kv0 += 128) {
            f32x4 s[2];
            s[0] = zero; s[1] = zero;
#pragma unroll
            for (int t = 0; t < 2; t++)
#pragma unroll
                for (int c = 0; c < 4; c++)
                    s[t] = MFMA16(aq[c], kc[t * 4 + c], s[t]);

#pragma unroll
            for (int ht = 0; ht < 8; ht++)
                vc[ht] = *(const bf16x8*)(vb + (size_t)(ht * 16 + m16) * T + kv0 + g * 8);

            const int kvn = kv0 + 128;
            if (kvn < kv_end) {
#pragma unroll
                for (int t = 0; t < 2; t++)
#pragma unroll
                    for (int c = 0; c < 4; c++)
                        kn[t * 4 + c] = *(const bf16x8*)(kb + (size_t)(kvn + t * 16 + m16) * H + c * 32 + g * 8);
            }

            float p0v[4], p1v[4];
#pragma unroll
            for (int ri = 0; ri < 4; ri++) {
                const int row = q0 + g * 4 + ri;
                float v0 = s[0][ri];
                float v1 = s[1][ri];
                if (kv0 + m16 > row) v0 = -1e30f;
                if (kv0 + 16 + m16 > row) v1 = -1e30f;
                float rm = fmaxf(v0, v1);
#pragma unroll
                for (int off = 1; off < 16; off <<= 1) rm = fmaxf(rm, __shfl_xor(rm, off));
                const float mnew = fmaxf(mst[ri], rm);
                const float alpha = __expf(mst[ri] - mnew);
                mst[ri] = mnew;
                p0v[ri] = __expf(v0 - mnew);
                p1v[ri] = __expf(v1 - mnew);
#pragma unroll
                for (int ht = 0; ht < 9; ht++) acc[ht][ri] *= alpha;
            }

#pragma unroll
            for (int ri = 0; ri < 4; ri++) {
                sm.at.pbuf[w][g * 4 + ri][m16] = (bf16_t)p0v[ri];
                sm.at.pbuf[w][g * 4 + ri][16 + m16] = (bf16_t)p1v[ri];
            }
            bf16x8 ap = *(const bf16x8*)(&sm.at.pbuf[w][m16][g * 8]);

#pragma unroll
            for (int ht = 0; ht < 8; ht++)
                acc[ht] = MFMA16(ap, vc[ht], acc[ht]);
            acc[8] = MFMA16(ap, ones, acc[8]);

#pragma unroll
            for (int i = 0; i < 8; i++) kc[i] = kn[i];
        }

        if (m16 == 0) {
#pragma unroll
            for (int ri = 0; ri < 4; ri++) sm.at.mred[w][g * 4 + ri] = mst[ri];
        }
        __syncthreads();
        float scale[4];
#pragma unroll
        for (int ri = 0; ri < 4; ri++) {
            const int row = g * 4 + ri;
            float mt = fmaxf(fmaxf(sm.at.mred[0][row], sm.at.mred[1][row]),
                             fmaxf(sm.at.mred[2][row], sm.at.mred[3][row]));
            scale[ri] = __expf(mst[ri] - mt);
        }
        if (m16 == 0) {
#pragma unroll
            for (int ri = 0; ri < 4; ri++) sm.at.lred[w][g * 4 + ri] = acc[8][ri] * scale[ri];
        }
#pragma unroll
        for (int ht = 0; ht < 8; ht++)
#pragma unroll
            for (int ri = 0; ri < 4; ri++)
                sm.at.accw[w][g * 4 + ri][ht * 16 + m16] = acc[ht][ri] * scale[ri];
        __syncthreads();

        float* ob = out + ((size_t)b * T + q0) * H;
        for (int e = tid; e < 16 * 128; e += 256) {
            const int row = e >> 7, col = e & 127;
            float o = sm.at.accw[0][row][col] + sm.at.accw[1][row][col] +
                      sm.at.accw[2][row][col] + sm.at.accw[3][row][col];
            float l = sm.at.lred[0][row] + sm.at.lred[1][row] +
                      sm.at.lred[2][row] + sm.at.lred[3][row];
            ob[(size_t)row * H + col] = o / l;
        }
    }
}

// ---------------------------------------------------------------------------
extern "C" void kernel_launch(void* const* d_in, const int* in_sizes, int n_in,
                              void* d_out, int out_size, void* d_ws, size_t ws_size,
                              hipStream_t stream) {
    const float* x = (const float*)d_in[0];
    const float* Wq = (const float*)d_in[1];
    const float* Wk = (const float*)d_in[2];
    const float* Wv = (const float*)d_in[3];
    float* out = (float*)d_out;

    char* ws = (char*)d_ws;
    bf16_t* Wt = (bf16_t*)ws;                     // 768 KiB
    char* p = ws + 786432;
    bf16_t* qb = (bf16_t*)(p);                    // 2 MiB each
    bf16_t* kb = (bf16_t*)(p + 2097152);
    bf16_t* vt = (bf16_t*)(p + 2 * 2097152);      // Vt[B][H][T]
    int* flag = (int*)(p + 3 * 2097152);          // barrier counter

    hipMemsetAsync(flag, 0, 4, stream);
    hipLaunchKernelGGL(fused, dim3(512), dim3(256), 0, stream,
                       x, Wq, Wk, Wv, Wt, qb, kb, vt, out, flag);
}

// Round 12
// 166.996 us; speedup vs baseline: 1.9316x; 1.9316x over previous
//
#include <hip/hip_runtime.h>
#include <hip/hip_bf16.h>
#include <cstdint>

// Problem: single attention head, B=4 T=2048 C=1024 H=128, causal, scale = C^-0.5.
// Inputs fp32: x[B,T,C], Wq/Wk/Wv[C,H], mask[T,T] int32 (tril, ignored).
// Output fp32 [B,T,H].
//
// R12: revert R11's fused-barrier design (265us serialization). 3 kernels:
//   1) transpose_w: W->Wt[3][H][C] bf16 (tiny)
//   2) proj: fp32 A staged straight from x via global_load_lds(16B) dbuf
//      (convert_x ELIMINATED); B from Wt; 64Mx128N/block; q pre-scaled 1/32
//   3) attn v5: 512-thr blocks, 8-way KV split -> 16 waves/CU (2x R8),
//      reverse-pair balance, ones-column l, K/V prefetch, LDS tree combine

typedef __bf16 bf16_t;
typedef __bf16 bf16x4 __attribute__((ext_vector_type(4)));
typedef __bf16 bf16x8 __attribute__((ext_vector_type(8)));
typedef float f32x4 __attribute__((ext_vector_type(4)));

#define MFMA16(a, b, c) __builtin_amdgcn_mfma_f32_16x16x32_bf16(a, b, c, 0, 0, 0)

constexpr int T = 2048;
constexpr int C = 1024;
constexpr int H = 128;
constexpr int BK = 64;

__device__ inline void gld16(const void* g, void* l) {
    __builtin_amdgcn_global_load_lds(
        (const __attribute__((address_space(1))) unsigned int*)g,
        (__attribute__((address_space(3))) unsigned int*)l, 16, 0, 0);
}

// ---------------------------------------------------------------------------
// Kernel 1: W[C][H] fp32 -> Wt[z][H][C] bf16. grid 384, block 256.
__global__ __launch_bounds__(256) void transpose_w(const float* __restrict__ Wq,
                                                   const float* __restrict__ Wk,
                                                   const float* __restrict__ Wv,
                                                   bf16_t* __restrict__ Wt) {
    __shared__ bf16_t tile[32][34];
    const int tid = threadIdx.x, blk = blockIdx.x;
    const int z = blk >> 7, rem = blk & 127;
    const int c0 = (rem & 31) * 32, h0 = (rem >> 5) * 32;
    const float* W = z == 0 ? Wq : (z == 1 ? Wk : Wv);
    const int tx = tid & 31, ty = tid >> 5;
#pragma unroll
    for (int i = 0; i < 4; i++)
        tile[ty + 8 * i][tx] = (bf16_t)W[(size_t)(c0 + ty + 8 * i) * H + h0 + tx];
    __syncthreads();
    bf16_t* Wtz = Wt + (size_t)z * H * C;
#pragma unroll
    for (int i = 0; i < 4; i++)
        Wtz[(size_t)(h0 + ty + 8 * i) * C + c0 + tx] = tile[tx][ty + 8 * i];
}

// ---------------------------------------------------------------------------
// Kernel 2: y = x @ W, fp32 A staged via global_load_lds, bf16 B from Wt.
// Block: 64M x 128N, 4 waves of 32x64. BK=64 dbuf. grid (128,3), block 256.
// A swizzle (fp32, 4-float groups): v = c4 ^ (r&15). B: v = c8 ^ (r&7).
// z==0 (q) epilogue folds in C^-0.5 = 1/32.
__global__ __launch_bounds__(256) void proj_gemm(const float* __restrict__ x,
                                                 const bf16_t* __restrict__ Wt,
                                                 bf16_t* __restrict__ qout,
                                                 bf16_t* __restrict__ kout,
                                                 bf16_t* __restrict__ vtout) {
    __shared__ __align__(16) float Ab[2][64 * BK];     // 16 KiB each
    __shared__ __align__(16) bf16_t Bb[2][128 * BK];   // 16 KiB each
    const int tid = threadIdx.x;
    const int w = tid >> 6, lane = tid & 63;
    const int m16 = lane & 15, g = lane >> 4;
    const int wm = w & 1, wn = w >> 1;
    const int z = blockIdx.y;
    const int m0 = blockIdx.x * 64;
    const bf16_t* Bsrc = Wt + (size_t)z * H * C;

    auto stage = [&](int s, int k0) {
#pragma unroll
        for (int i = 0; i < 4; i++) {              // A: e in [0,1024)
            const int e = i * 256 + tid;
            const int r = e >> 4, v = e & 15, c4 = v ^ (r & 15);
            gld16(x + (size_t)(m0 + r) * C + k0 + c4 * 4, &Ab[s][(i * 4 + w) * 256]);
        }
#pragma unroll
        for (int i = 0; i < 4; i++) {              // B: e in [0,1024)
            const int e = i * 256 + tid;
            const int r = e >> 3, v = e & 7, c8 = v ^ (r & 7);
            gld16(Bsrc + (size_t)r * C + k0 + c8 * 8, &Bb[s][(i * 4 + w) * 512]);
        }
    };

    f32x4 zero = {0.f, 0.f, 0.f, 0.f};
    f32x4 acc[2][4];
#pragma unroll
    for (int mf = 0; mf < 2; mf++)
#pragma unroll
        for (int nf = 0; nf < 4; nf++) acc[mf][nf] = zero;

    stage(0, 0);
    for (int c = 0; c < C / BK; c++) {
        __syncthreads();
        if (c + 1 < C / BK) stage((c + 1) & 1, (c + 1) * BK);
        const int s = c & 1;

        bf16x8 af[2][2], bfr[4][2];
#pragma unroll
        for (int mf = 0; mf < 2; mf++)
#pragma unroll
            for (int kf = 0; kf < 2; kf++) {
                const int r = wm * 32 + mf * 16 + m16;
                const int c4 = kf * 8 + g * 2;
                const int va = c4 ^ (r & 15), vb = (c4 + 1) ^ (r & 15);
                float4 fa = *(const float4*)(&Ab[s][r * BK + va * 4]);
                float4 fb = *(const float4*)(&Ab[s][r * BK + vb * 4]);
                bf16x8 t;
                t[0] = (bf16_t)fa.x; t[1] = (bf16_t)fa.y;
                t[2] = (bf16_t)fa.z; t[3] = (bf16_t)fa.w;
                t[4] = (bf16_t)fb.x; t[5] = (bf16_t)fb.y;
                t[6] = (bf16_t)fb.z; t[7] = (bf16_t)fb.w;
                af[mf][kf] = t;
            }
#pragma unroll
        for (int nf = 0; nf < 4; nf++)
#pragma unroll
            for (int kf = 0; kf < 2; kf++) {
                const int r = wn * 64 + nf * 16 + m16;
                const int v = (kf * 4 + g) ^ (r & 7);
                bfr[nf][kf] = *(const bf16x8*)(&Bb[s][r * BK + v * 8]);
            }
#pragma unroll
        for (int kf = 0; kf < 2; kf++)
#pragma unroll
            for (int mf = 0; mf < 2; mf++)
#pragma unroll
                for (int nf = 0; nf < 4; nf++)
                    acc[mf][nf] = MFMA16(af[mf][kf], bfr[nf][kf], acc[mf][nf]);
    }

    const float sc = (z == 0) ? 0.03125f : 1.0f;   // fold C^-0.5 into q
    if (z < 2) {
        bf16_t* o = (z == 0) ? qout : kout;
#pragma unroll
        for (int mf = 0; mf < 2; mf++)
#pragma unroll
            for (int nf = 0; nf < 4; nf++)
#pragma unroll
                for (int ri = 0; ri < 4; ri++) {
                    const int r = m0 + wm * 32 + mf * 16 + g * 4 + ri;
                    const int n = wn * 64 + nf * 16 + m16;
                    o[(size_t)r * H + n] = (bf16_t)(acc[mf][nf][ri] * sc);
                }
    } else {
#pragma unroll
        for (int mf = 0; mf < 2; mf++) {
            const int t0 = m0 + wm * 32 + mf * 16 + g * 4;
            const int bidx = t0 >> 11, tt = t0 & (T - 1);
#pragma unroll
            for (int nf = 0; nf < 4; nf++) {
                const int h = wn * 64 + nf * 16 + m16;
                bf16x4 vv;
#pragma unroll
                for (int ri = 0; ri < 4; ri++) vv[ri] = (bf16_t)acc[mf][nf][ri];
                *(bf16x4*)(vtout + ((size_t)bidx * H + h) * T + tt) = vv;
            }
        }
    }
}

// ---------------------------------------------------------------------------
// Kernel 3: flash attention v5. 512-thr blocks (8 waves), 8-way KV split on a
// 16-row Q tile; 512 blocks reverse-paired -> 16 waves/CU. ones-column l,
// K/V prefetch, pairwise LDS tree combine. q pre-scaled by C^-0.5.
__global__ __launch_bounds__(512, 4) void attn(const bf16_t* __restrict__ q,
                                               const bf16_t* __restrict__ k,
                                               const bf16_t* __restrict__ vt,
                                               float* __restrict__ out) {
    __shared__ float buf[4][16][128];              // 32 KiB (tree combine)
    __shared__ __align__(16) bf16_t pbuf[8][16][40];
    __shared__ float mred[8][16], lred[8][16];
    const int tid = threadIdx.x;
    const int w = tid >> 6;                        // 0..7
    const int lane = tid & 63;
    const int m16 = lane & 15, g = lane >> 4;
    const int b = blockIdx.x & 3;
    const int kk = blockIdx.x >> 2;                // 0..127
    const int qt = (kk < 64) ? kk : 191 - kk;      // reverse-pair balance
    const int q0 = qt * 16;

    const bf16_t* qb = q + (size_t)b * T * H;
    const bf16_t* kb = k + (size_t)b * T * H;
    const bf16_t* vb = vt + (size_t)b * H * T;

    bf16x8 aq[4];
#pragma unroll
    for (int c = 0; c < 4; c++)
        aq[c] = *(const bf16x8*)(qb + (size_t)(q0 + m16) * H + c * 32 + g * 8);

    bf16x8 ones;
#pragma unroll
    for (int i = 0; i < 8; i++) ones[i] = (bf16_t)1.0f;

    f32x4 zero = {0.f, 0.f, 0.f, 0.f};
    f32x4 acc[9];                                  // [8] = row-sum (l)
#pragma unroll
    for (int ht = 0; ht < 9; ht++) acc[ht] = zero;
    float mst[4];
#pragma unroll
    for (int ri = 0; ri < 4; ri++) mst[ri] = -1e30f;

    const int kv_end = q0 + 16;
    bf16x8 kc[8], kn[8], vc[8];
    int kv0 = w * 32;
    if (kv0 < kv_end) {
#pragma unroll
        for (int t = 0; t < 2; t++)
#pragma unroll
            for (int c = 0; c < 4; c++)
                kc[t * 4 + c] = *(const bf16x8*)(kb + (size_t)(kv0 + t * 16 + m16) * H + c * 32 + g * 8);
    }

    for (; kv0 < kv_end; kv0 += 256) {             // 8 waves x 32
        f32x4 s[2];
        s[0] = zero; s[1] = zero;
#pragma unroll
        for (int t = 0; t < 2; t++)
#pragma unroll
            for (int c = 0; c < 4; c++)
                s[t] = MFMA16(aq[c], kc[t * 4 + c], s[t]);

#pragma unroll
        for (int ht = 0; ht < 8; ht++)
            vc[ht] = *(const bf16x8*)(vb + (size_t)(ht * 16 + m16) * T + kv0 + g * 8);

        const int kvn = kv0 + 256;
        if (kvn < kv_end) {
#pragma unroll
            for (int t = 0; t < 2; t++)
#pragma unroll
                for (int c = 0; c < 4; c++)
                    kn[t * 4 + c] = *(const bf16x8*)(kb + (size_t)(kvn + t * 16 + m16) * H + c * 32 + g * 8);
        }

        float p0v[4], p1v[4];
#pragma unroll
        for (int ri = 0; ri < 4; ri++) {
            const int row = q0 + g * 4 + ri;
            float v0 = s[0][ri];
            float v1 = s[1][ri];
            if (kv0 + m16 > row) v0 = -1e30f;
            if (kv0 + 16 + m16 > row) v1 = -1e30f;
            float rm = fmaxf(v0, v1);
#pragma unroll
            for (int off = 1; off < 16; off <<= 1) rm = fmaxf(rm, __shfl_xor(rm, off));
            const float mnew = fmaxf(mst[ri], rm);
            const float alpha = __expf(mst[ri] - mnew);
            mst[ri] = mnew;
            p0v[ri] = __expf(v0 - mnew);
            p1v[ri] = __expf(v1 - mnew);
#pragma unroll
            for (int ht = 0; ht < 9; ht++) acc[ht][ri] *= alpha;
        }

#pragma unroll
        for (int ri = 0; ri < 4; ri++) {
            pbuf[w][g * 4 + ri][m16] = (bf16_t)p0v[ri];
            pbuf[w][g * 4 + ri][16 + m16] = (bf16_t)p1v[ri];
        }
        bf16x8 ap = *(const bf16x8*)(&pbuf[w][m16][g * 8]);

#pragma unroll
        for (int ht = 0; ht < 8; ht++)
            acc[ht] = MFMA16(ap, vc[ht], acc[ht]);
        acc[8] = MFMA16(ap, ones, acc[8]);

#pragma unroll
        for (int i = 0; i < 8; i++) kc[i] = kn[i];
    }

    // ---- combine: global m, scale, then pairwise O tree 8->4->2->1 ----
    if (m16 == 0) {
#pragma unroll
        for (int ri = 0; ri < 4; ri++) mred[w][g * 4 + ri] = mst[ri];
    }
    __syncthreads();
    float scale[4];
#pragma unroll
    for (int ri = 0; ri < 4; ri++) {
        const int row = g * 4 + ri;
        float mt = mred[0][row];
#pragma unroll
        for (int j = 1; j < 8; j++) mt = fmaxf(mt, mred[j][row]);
        scale[ri] = __expf(mst[ri] - mt);
    }
    if (m16 == 0) {
#pragma unroll
        for (int ri = 0; ri < 4; ri++) lred[w][g * 4 + ri] = acc[8][ri] * scale[ri];
    }
#pragma unroll
    for (int ht = 0; ht < 8; ht++)
#pragma unroll
        for (int ri = 0; ri < 4; ri++) acc[ht][ri] *= scale[ri];

    if (w >= 4) {
#pragma unroll
        for (int ht = 0; ht < 8; ht++)
#pragma unroll
            for (int ri = 0; ri < 4; ri++)
                buf[w - 4][g * 4 + ri][ht * 16 + m16] = acc[ht][ri];
    }
    __syncthreads();
    if (w < 4) {
#pragma unroll
        for (int ht = 0; ht < 8; ht++)
#pragma unroll
            for (int ri = 0; ri < 4; ri++)
                acc[ht][ri] += buf[w][g * 4 + ri][ht * 16 + m16];
    }
    __syncthreads();
    if (w == 2 || w == 3) {
#pragma unroll
        for (int ht = 0; ht < 8; ht++)
#pragma unroll
            for (int ri = 0; ri < 4; ri++)
                buf[w - 2][g * 4 + ri][ht * 16 + m16] = acc[ht][ri];
    }
    __syncthreads();
    if (w < 2) {
#pragma unroll
        for (int ht = 0; ht < 8; ht++)
#pragma unroll
            for (int ri = 0; ri < 4; ri++)
                acc[ht][ri] += buf[w][g * 4 + ri][ht * 16 + m16];
    }
    __syncthreads();
    if (w == 1) {
#pragma unroll
        for (int ht = 0; ht < 8; ht++)
#pragma unroll
            for (int ri = 0; ri < 4; ri++)
                buf[1][g * 4 + ri][ht * 16 + m16] = acc[ht][ri];
    }
    __syncthreads();
    if (w == 0) {
        float* ob = out + ((size_t)b * T + q0) * H;
#pragma unroll
        for (int ri = 0; ri < 4; ri++) {
            const int row = g * 4 + ri;
            float lt = lred[0][row];
#pragma unroll
            for (int j = 1; j < 8; j++) lt += lred[j][row];
            const float inv = 1.f / lt;
#pragma unroll
            for (int ht = 0; ht < 8; ht++)
                ob[(size_t)row * H + ht * 16 + m16] =
                    (acc[ht][ri] + buf[1][row][ht * 16 + m16]) * inv;
        }
    }
}

// ---------------------------------------------------------------------------
extern "C" void kernel_launch(void* const* d_in, const int* in_sizes, int n_in,
                              void* d_out, int out_size, void* d_ws, size_t ws_size,
                              hipStream_t stream) {
    const float* x = (const float*)d_in[0];
    const float* Wq = (const float*)d_in[1];
    const float* Wk = (const float*)d_in[2];
    const float* Wv = (const float*)d_in[3];
    float* out = (float*)d_out;

    char* ws = (char*)d_ws;
    bf16_t* Wt = (bf16_t*)ws;                     // 768 KiB
    char* p = ws + 786432;
    bf16_t* qb = (bf16_t*)(p);                    // 2 MiB each
    bf16_t* kb = (bf16_t*)(p + 2097152);
    bf16_t* vt = (bf16_t*)(p + 2 * 2097152);      // Vt[B][H][T]

    hipLaunchKernelGGL(transpose_w, dim3(384), dim3(256), 0, stream,
                       Wq, Wk, Wv, Wt);
    hipLaunchKernelGGL(proj_gemm, dim3(128, 3), dim3(256), 0, stream,
                       x, Wt, qb, kb, vt);
    hipLaunchKernelGGL(attn, dim3(512), dim3(512), 0, stream,
                       qb, kb, vt, out);
}

// Round 13
// 157.633 us; speedup vs baseline: 2.0463x; 1.0594x over previous
//
#include <hip/hip_runtime.h>
#include <hip/hip_bf16.h>
#include <cstdint>

// Problem: single attention head, B=4 T=2048 C=1024 H=128, causal, scale = C^-0.5.
// Inputs fp32: x[B,T,C], Wq/Wk/Wv[C,H], mask[T,T] int32 (tril, ignored).
// Output fp32 [B,T,H].
//
// R13: R8 prep+proj restored (best measured). attn = 8-way KV split WITHOUT
// the R12 spill: launch_bounds(512,2) (256-VGPR cap), kn-prefetch dropped
// (-32 VGPRs), LPT block order (heavy qt first).
//   0) prep: x fp32->bf16 + W->Wt[3][H][C]
//   1) proj: 64Mx128N/block, BK=64, global_load_lds(16B) dbuf, xor swizzle
//   2) attn v6: 512 thr, 8-way KV split on 16-row Q tile, ones-column l,
//      V-issue before softmax, LDS tree combine, LPT order

typedef __bf16 bf16_t;
typedef __bf16 bf16x4 __attribute__((ext_vector_type(4)));
typedef __bf16 bf16x8 __attribute__((ext_vector_type(8)));
typedef float f32x4 __attribute__((ext_vector_type(4)));

#define MFMA16(a, b, c) __builtin_amdgcn_mfma_f32_16x16x32_bf16(a, b, c, 0, 0, 0)

constexpr int T = 2048;
constexpr int C = 1024;
constexpr int H = 128;
constexpr int BK = 64;

__device__ inline bf16x8 load8f(const float* __restrict__ p) {
    float4 a = *(const float4*)p;
    float4 b = *(const float4*)(p + 4);
    bf16x8 r;
    r[0] = (bf16_t)a.x; r[1] = (bf16_t)a.y; r[2] = (bf16_t)a.z; r[3] = (bf16_t)a.w;
    r[4] = (bf16_t)b.x; r[5] = (bf16_t)b.y; r[6] = (bf16_t)b.z; r[7] = (bf16_t)b.w;
    return r;
}

__device__ inline void gld16(const void* g, void* l) {
    __builtin_amdgcn_global_load_lds(
        (const __attribute__((address_space(1))) unsigned int*)g,
        (__attribute__((address_space(3))) unsigned int*)l, 16, 0, 0);
}

// ---------------------------------------------------------------------------
// Kernel 0: fused prep. Blocks [0,2048): x fp32->bf16. Blocks [2048,2432):
// W[C][H] -> Wt[z][H][C] bf16. block 256.
__global__ __launch_bounds__(256) void prep(const float* __restrict__ x,
                                            const float* __restrict__ Wq,
                                            const float* __restrict__ Wk,
                                            const float* __restrict__ Wv,
                                            bf16_t* __restrict__ xb,
                                            bf16_t* __restrict__ Wt) {
    const int t = threadIdx.x;
    if (blockIdx.x < 2048) {
        const int n8 = 4 * T * C / 8;
        int i = blockIdx.x * 256 + t;
        for (; i < n8; i += 2048 * 256)
            *(bf16x8*)(xb + (size_t)i * 8) = load8f(x + (size_t)i * 8);
    } else {
        __shared__ bf16_t tile[32][34];
        const int b2 = blockIdx.x - 2048;
        const int z = b2 >> 7, rem = b2 & 127;
        const int c0 = (rem & 31) * 32, h0 = (rem >> 5) * 32;
        const float* W = z == 0 ? Wq : (z == 1 ? Wk : Wv);
        const int tx = t & 31, ty = t >> 5;
#pragma unroll
        for (int i = 0; i < 4; i++)
            tile[ty + 8 * i][tx] = (bf16_t)W[(size_t)(c0 + ty + 8 * i) * H + h0 + tx];
        __syncthreads();
        bf16_t* Wtz = Wt + (size_t)z * H * C;
#pragma unroll
        for (int i = 0; i < 4; i++)
            Wtz[(size_t)(h0 + ty + 8 * i) * C + c0 + tx] = tile[tx][ty + 8 * i];
    }
}

// ---------------------------------------------------------------------------
// Kernel 1: y = xb @ W (R8 body). 64Mx128N/block, BK=64, dbuf LDS via
// global_load_lds(16B), xor swizzle on global side. grid (128,3), block 256.
__global__ __launch_bounds__(256) void proj_gemm(const bf16_t* __restrict__ xb,
                                                 const bf16_t* __restrict__ Wt,
                                                 bf16_t* __restrict__ qout,
                                                 bf16_t* __restrict__ kout,
                                                 bf16_t* __restrict__ vtout) {
    __shared__ __align__(16) bf16_t Ab[2][64 * BK];
    __shared__ __align__(16) bf16_t Bb[2][128 * BK];
    const int t = threadIdx.x;
    const int w = t >> 6, lane = t & 63;
    const int m16 = lane & 15, g = lane >> 4;
    const int wm = w & 1, wn = w >> 1;
    const int z = blockIdx.y;
    const int m0 = blockIdx.x * 64;
    const bf16_t* Bsrc = Wt + (size_t)z * H * C;

    auto stage = [&](int s, int k0) {
#pragma unroll
        for (int i = 0; i < 2; i++) {
            const int e = i * 256 + t;
            const int r = e >> 3, v = e & 7, c8 = v ^ (r & 7);
            gld16(xb + (size_t)(m0 + r) * C + k0 + c8 * 8, &Ab[s][(i * 4 + w) * 512]);
        }
#pragma unroll
        for (int i = 0; i < 4; i++) {
            const int e = i * 256 + t;
            const int r = e >> 3, v = e & 7, c8 = v ^ (r & 7);
            gld16(Bsrc + (size_t)r * C + k0 + c8 * 8, &Bb[s][(i * 4 + w) * 512]);
        }
    };

    f32x4 zero = {0.f, 0.f, 0.f, 0.f};
    f32x4 acc[2][4];
#pragma unroll
    for (int mf = 0; mf < 2; mf++)
#pragma unroll
        for (int nf = 0; nf < 4; nf++) acc[mf][nf] = zero;

    stage(0, 0);
    for (int c = 0; c < C / BK; c++) {
        __syncthreads();
        if (c + 1 < C / BK) stage((c + 1) & 1, (c + 1) * BK);
        const int s = c & 1;

        bf16x8 af[2][2], bfr[4][2];
#pragma unroll
        for (int mf = 0; mf < 2; mf++)
#pragma unroll
            for (int kf = 0; kf < 2; kf++) {
                const int r = wm * 32 + mf * 16 + m16;
                const int v = (kf * 4 + g) ^ (r & 7);
                af[mf][kf] = *(const bf16x8*)(&Ab[s][r * BK + v * 8]);
            }
#pragma unroll
        for (int nf = 0; nf < 4; nf++)
#pragma unroll
            for (int kf = 0; kf < 2; kf++) {
                const int r = wn * 64 + nf * 16 + m16;
                const int v = (kf * 4 + g) ^ (r & 7);
                bfr[nf][kf] = *(const bf16x8*)(&Bb[s][r * BK + v * 8]);
            }
#pragma unroll
        for (int kf = 0; kf < 2; kf++)
#pragma unroll
            for (int mf = 0; mf < 2; mf++)
#pragma unroll
                for (int nf = 0; nf < 4; nf++)
                    acc[mf][nf] = MFMA16(af[mf][kf], bfr[nf][kf], acc[mf][nf]);
    }

    const float sc = (z == 0) ? 0.03125f : 1.0f;
    if (z < 2) {
        bf16_t* o = (z == 0) ? qout : kout;
#pragma unroll
        for (int mf = 0; mf < 2; mf++)
#pragma unroll
            for (int nf = 0; nf < 4; nf++)
#pragma unroll
                for (int ri = 0; ri < 4; ri++) {
                    const int r = m0 + wm * 32 + mf * 16 + g * 4 + ri;
                    const int n = wn * 64 + nf * 16 + m16;
                    o[(size_t)r * H + n] = (bf16_t)(acc[mf][nf][ri] * sc);
                }
    } else {
#pragma unroll
        for (int mf = 0; mf < 2; mf++) {
            const int t0 = m0 + wm * 32 + mf * 16 + g * 4;
            const int bidx = t0 >> 11, tt = t0 & (T - 1);
#pragma unroll
            for (int nf = 0; nf < 4; nf++) {
                const int h = wn * 64 + nf * 16 + m16;
                bf16x4 vv;
#pragma unroll
                for (int ri = 0; ri < 4; ri++) vv[ri] = (bf16_t)acc[mf][nf][ri];
                *(bf16x4*)(vtout + ((size_t)bidx * H + h) * T + tt) = vv;
            }
        }
    }
}

// ---------------------------------------------------------------------------
// Kernel 2: flash attention v6. 512-thr blocks (8 waves), 8-way KV split on a
// 16-row Q tile. NO kn prefetch (spill fix). LPT order: heaviest qt first.
// launch_bounds(512,2): 256-VGPR cap -> no scratch. grid 512, block 512.
__global__ __launch_bounds__(512, 2) void attn(const bf16_t* __restrict__ q,
                                               const bf16_t* __restrict__ k,
                                               const bf16_t* __restrict__ vt,
                                               float* __restrict__ out) {
    __shared__ float buf[4][16][128];              // 32 KiB tree combine
    __shared__ __align__(16) bf16_t pbuf[8][16][40];
    __shared__ float mred[8][16], lred[8][16];
    const int tid = threadIdx.x;
    const int w = tid >> 6;                        // 0..7
    const int lane = tid & 63;
    const int m16 = lane & 15, g = lane >> 4;
    const int b = blockIdx.x & 3;
    const int kk = blockIdx.x >> 2;                // 0..127
    const int qt = 127 - kk;                       // LPT: heavy first
    const int q0 = qt * 16;

    const bf16_t* qb = q + (size_t)b * T * H;
    const bf16_t* kb = k + (size_t)b * T * H;
    const bf16_t* vb = vt + (size_t)b * H * T;

    bf16x8 aq[4];
#pragma unroll
    for (int c = 0; c < 4; c++)
        aq[c] = *(const bf16x8*)(qb + (size_t)(q0 + m16) * H + c * 32 + g * 8);

    bf16x8 ones;
#pragma unroll
    for (int i = 0; i < 8; i++) ones[i] = (bf16_t)1.0f;

    f32x4 zero = {0.f, 0.f, 0.f, 0.f};
    f32x4 acc[9];                                  // [8] = row-sum (l)
#pragma unroll
    for (int ht = 0; ht < 9; ht++) acc[ht] = zero;
    float mst[4];
#pragma unroll
    for (int ri = 0; ri < 4; ri++) mst[ri] = -1e30f;

    const int kv_end = q0 + 16;
    for (int kv0 = w * 32; kv0 < kv_end; kv0 += 256) {   // 8 waves x 32
        bf16x8 kc[8], vc[8];
#pragma unroll
        for (int t = 0; t < 2; t++)
#pragma unroll
            for (int c = 0; c < 4; c++)
                kc[t * 4 + c] = *(const bf16x8*)(kb + (size_t)(kv0 + t * 16 + m16) * H + c * 32 + g * 8);

        f32x4 s[2];
        s[0] = zero; s[1] = zero;
#pragma unroll
        for (int t = 0; t < 2; t++)
#pragma unroll
            for (int c = 0; c < 4; c++)
                s[t] = MFMA16(aq[c], kc[t * 4 + c], s[t]);

        // V issued before softmax (latency covered by softmax VALU)
#pragma unroll
        for (int ht = 0; ht < 8; ht++)
            vc[ht] = *(const bf16x8*)(vb + (size_t)(ht * 16 + m16) * T + kv0 + g * 8);

        float p0v[4], p1v[4];
#pragma unroll
        for (int ri = 0; ri < 4; ri++) {
            const int row = q0 + g * 4 + ri;
            float v0 = s[0][ri];
            float v1 = s[1][ri];
            if (kv0 + m16 > row) v0 = -1e30f;
            if (kv0 + 16 + m16 > row) v1 = -1e30f;
            float rm = fmaxf(v0, v1);
#pragma unroll
            for (int off = 1; off < 16; off <<= 1) rm = fmaxf(rm, __shfl_xor(rm, off));
            const float mnew = fmaxf(mst[ri], rm);
            const float alpha = __expf(mst[ri] - mnew);
            mst[ri] = mnew;
            p0v[ri] = __expf(v0 - mnew);
            p1v[ri] = __expf(v1 - mnew);
#pragma unroll
            for (int ht = 0; ht < 9; ht++) acc[ht][ri] *= alpha;
        }

#pragma unroll
        for (int ri = 0; ri < 4; ri++) {
            pbuf[w][g * 4 + ri][m16] = (bf16_t)p0v[ri];
            pbuf[w][g * 4 + ri][16 + m16] = (bf16_t)p1v[ri];
        }
        bf16x8 ap = *(const bf16x8*)(&pbuf[w][m16][g * 8]);

#pragma unroll
        for (int ht = 0; ht < 8; ht++)
            acc[ht] = MFMA16(ap, vc[ht], acc[ht]);
        acc[8] = MFMA16(ap, ones, acc[8]);
    }

    // ---- combine: global m, scale, pairwise O tree 8->4->2->1 ----
    if (m16 == 0) {
#pragma unroll
        for (int ri = 0; ri < 4; ri++) mred[w][g * 4 + ri] = mst[ri];
    }
    __syncthreads();
    float scale[4];
#pragma unroll
    for (int ri = 0; ri < 4; ri++) {
        const int row = g * 4 + ri;
        float mt = mred[0][row];
#pragma unroll
        for (int j = 1; j < 8; j++) mt = fmaxf(mt, mred[j][row]);
        scale[ri] = __expf(mst[ri] - mt);
    }
    if (m16 == 0) {
#pragma unroll
        for (int ri = 0; ri < 4; ri++) lred[w][g * 4 + ri] = acc[8][ri] * scale[ri];
    }
#pragma unroll
    for (int ht = 0; ht < 8; ht++)
#pragma unroll
        for (int ri = 0; ri < 4; ri++) acc[ht][ri] *= scale[ri];

    if (w >= 4) {
#pragma unroll
        for (int ht = 0; ht < 8; ht++)
#pragma unroll
            for (int ri = 0; ri < 4; ri++)
                buf[w - 4][g * 4 + ri][ht * 16 + m16] = acc[ht][ri];
    }
    __syncthreads();
    if (w < 4) {
#pragma unroll
        for (int ht = 0; ht < 8; ht++)
#pragma unroll
            for (int ri = 0; ri < 4; ri++)
                acc[ht][ri] += buf[w][g * 4 + ri][ht * 16 + m16];
    }
    __syncthreads();
    if (w == 2 || w == 3) {
#pragma unroll
        for (int ht = 0; ht < 8; ht++)
#pragma unroll
            for (int ri = 0; ri < 4; ri++)
                buf[w - 2][g * 4 + ri][ht * 16 + m16] = acc[ht][ri];
    }
    __syncthreads();
    if (w < 2) {
#pragma unroll
        for (int ht = 0; ht < 8; ht++)
#pragma unroll
            for (int ri = 0; ri < 4; ri++)
                acc[ht][ri] += buf[w][g * 4 + ri][ht * 16 + m16];
    }
    __syncthreads();
    if (w == 1) {
#pragma unroll
        for (int ht = 0; ht < 8; ht++)
#pragma unroll
            for (int ri = 0; ri < 4; ri++)
                buf[1][g * 4 + ri][ht * 16 + m16] = acc[ht][ri];
    }
    __syncthreads();
    if (w == 0) {
        float* ob = out + ((size_t)b * T + q0) * H;
#pragma unroll
        for (int ri = 0; ri < 4; ri++) {
            const int row = g * 4 + ri;
            float lt = lred[0][row];
#pragma unroll
            for (int j = 1; j < 8; j++) lt += lred[j][row];
            const float inv = 1.f / lt;
#pragma unroll
            for (int ht = 0; ht < 8; ht++)
                ob[(size_t)row * H + ht * 16 + m16] =
                    (acc[ht][ri] + buf[1][row][ht * 16 + m16]) * inv;
        }
    }
}

// ---------------------------------------------------------------------------
extern "C" void kernel_launch(void* const* d_in, const int* in_sizes, int n_in,
                              void* d_out, int out_size, void* d_ws, size_t ws_size,
                              hipStream_t stream) {
    const float* x = (const float*)d_in[0];
    const float* Wq = (const float*)d_in[1];
    const float* Wk = (const float*)d_in[2];
    const float* Wv = (const float*)d_in[3];
    float* out = (float*)d_out;

    char* ws = (char*)d_ws;
    bf16_t* xb = (bf16_t*)ws;                     // 16 MiB
    bf16_t* Wt = (bf16_t*)(ws + 16777216);        // 768 KiB
    char* p = ws + 16777216 + 786432;
    bf16_t* qb = (bf16_t*)(p);                    // 2 MiB each
    bf16_t* kb = (bf16_t*)(p + 2097152);
    bf16_t* vt = (bf16_t*)(p + 2 * 2097152);      // Vt[B][H][T]

    hipLaunchKernelGGL(prep, dim3(2048 + 384), dim3(256), 0, stream,
                       x, Wq, Wk, Wv, xb, Wt);
    hipLaunchKernelGGL(proj_gemm, dim3(128, 3), dim3(256), 0, stream,
                       xb, Wt, qb, kb, vt);
    hipLaunchKernelGGL(attn, dim3(512), dim3(512), 0, stream,
                       qb, kb, vt, out);
}